// Round 11
// baseline (398.666 us; speedup 1.0000x reference)
//
#include <hip/hip_runtime.h>

typedef unsigned int u32;
typedef unsigned long long u64;
typedef unsigned char u8;

#define NB 4
#define T_ANCH 261120
#define NCAND 2048          // candidates per image (4 levels x 512)
#define KSEL 512
#define POSTN 512
#define LOG_MAXF 4.135166556742356f
#define NMS_TH 0.7f
#define LVL_OFF_F 8192.0f
#define BINS 4096           // top-12 bits of mono32
#define EQCAP 8192          // tie-bin capacity (expected ~300-700 occupants)
#define PAIR_CAP (1u<<20)   // 1M compacted pairs
#define K4A_BLOCKS 2048     // 4 i-rows (8192 pairs) per block -> 32 KB LDS
#define K4A_ROWS 4
#define K1_BLOCKS 256       // 64 chunk-blocks per image (48/12/3/1 per level)

__device__ __forceinline__ u32 mono32(float f){
  u32 u = __float_as_uint(f);
  return (u & 0x80000000u) ? ~u : (u | 0x80000000u);
}
__device__ __forceinline__ int lvl_hw(int lvl){ return 65536 >> (2*lvl); }
__device__ __forceinline__ int lvl_off(int lvl){
  return (lvl>0?196608:0) + (lvl>1?49152:0) + (lvl>2?12288:0);
}
// chunk-block mapping: bx in [0,256): b = bx>>6, c = bx&63
__device__ __forceinline__ void k1_map(int bx, int& b, int& lvl, int& ch){
  b = bx >> 6;
  int c = bx & 63;
  if (c < 48){ lvl = 0; ch = c; }
  else if (c < 60){ lvl = 1; ch = c - 48; }
  else if (c < 63){ lvl = 2; ch = c - 60; }
  else { lvl = 3; ch = 0; }
}

// ---------------------------------------------------------------------------
// K1a: per-chunk private histogram of mono32>>20. 256 blocks, 1 float4/thread.
// ---------------------------------------------------------------------------
__global__ __launch_bounds__(1024) void k1a_hist(
    const float* __restrict__ o0, const float* __restrict__ o1,
    const float* __restrict__ o2, const float* __restrict__ o3,
    u32* __restrict__ ghist)
{
  int b, lvl, ch;
  k1_map(blockIdx.x, b, lvl, ch);
  const float* ob = (lvl==0)?o0 : (lvl==1)?o1 : (lvl==2)?o2 : o3;
  int hw = lvl_hw(lvl);
  int size = 3*hw;
  int n4 = size >> 2;
  int i4 = ch*1024 + threadIdx.x;
  __shared__ u32 hist[BINS];
  for (int i = threadIdx.x; i < BINS; i += 1024) hist[i] = 0;
  __syncthreads();
  if (i4 < n4){
    float4 v = ((const float4*)(ob + (size_t)b*size))[i4];
    atomicAdd(&hist[mono32(v.x) >> 20], 1u);
    atomicAdd(&hist[mono32(v.y) >> 20], 1u);
    atomicAdd(&hist[mono32(v.z) >> 20], 1u);
    atomicAdd(&hist[mono32(v.w) >> 20], 1u);
  }
  __syncthreads();
  u32* out = ghist + (size_t)blockIdx.x*BINS;
  for (int i = threadIdx.x; i < BINS; i += 1024) out[i] = hist[i];
}

// ---------------------------------------------------------------------------
// K1b: reduce chunk histograms per (b,lvl); serial threshold walk -> b0,
// cntAbove; zero emit/tie counters.
// ---------------------------------------------------------------------------
__global__ __launch_bounds__(1024) void k1b_thresh(
    const u32* __restrict__ ghist, u32* __restrict__ gb0,
    u32* __restrict__ gcA, u32* __restrict__ emitcnt, u32* __restrict__ tiecnt)
{
  int bid = blockIdx.x;               // 16 = (b,lvl)
  int b = bid >> 2, lvl = bid & 3;
  int base_bx = b*64 + (lvl==0?0 : lvl==1?48 : lvl==2?60 : 63);
  int nch = (lvl==0?48 : lvl==1?12 : lvl==2?3 : 1);
  __shared__ u32 hist[BINS];
  __shared__ u32 coarse[64];
  int t = threadIdx.x;
  u32 c0=0,c1=0,c2=0,c3=0;
  for (int ch = 0; ch < nch; ++ch){
    const u32* h = ghist + (size_t)(base_bx+ch)*BINS;
    c0 += h[4*t+0]; c1 += h[4*t+1]; c2 += h[4*t+2]; c3 += h[4*t+3];
  }
  hist[4*t+0]=c0; hist[4*t+1]=c1; hist[4*t+2]=c2; hist[4*t+3]=c3;
  __syncthreads();
  if (t < 64){
    u32 s = 0;
    for (int z = 0; z < 64; ++z) s += hist[t*64 + z];
    coarse[t] = s;
  }
  __syncthreads();
  if (t == 0){
    u32 acc = 0;
    int cb = 63;
    while (acc + coarse[cb] < (u32)KSEL){ acc += coarse[cb]; --cb; }
    int z = cb*64 + 63;
    while (acc + hist[z] < (u32)KSEL){ acc += hist[z]; --z; }
    gb0[bid] = (u32)z;
    gcA[bid] = acc;
    emitcnt[bid] = 0;
    tiecnt[bid] = 0;
  }
}

// ---------------------------------------------------------------------------
// K1c: classify chunk elements vs b0. LDS lists + ONE global reservation per
// list per block. Emits PERMUTED index j = pix*3 + a (see R4 notes).
// ---------------------------------------------------------------------------
__global__ __launch_bounds__(1024) void k1c_classify(
    const float* __restrict__ o0, const float* __restrict__ o1,
    const float* __restrict__ o2, const float* __restrict__ o3,
    const u32* __restrict__ gb0,
    u32* __restrict__ emitcnt, u32* __restrict__ tiecnt,
    int* __restrict__ cand_j, u64* __restrict__ gtie)
{
  int b, lvl, ch;
  k1_map(blockIdx.x, b, lvl, ch);
  int bid16 = b*4 + lvl;
  const float* ob = (lvl==0)?o0 : (lvl==1)?o1 : (lvl==2)?o2 : o3;
  int hw = lvl_hw(lvl);
  int size = 3*hw;
  int n4 = size >> 2;
  int i4 = ch*1024 + threadIdx.x;

  __shared__ u32 dbuf[KSEL];
  __shared__ u64 tbuf[4096];
  __shared__ u32 dn, tn, dbase, tbase;
  if (threadIdx.x == 0){ dn = 0; tn = 0; }
  __syncthreads();

  u32 b0v = gb0[bid16];
  if (i4 < n4){
    float4 v = ((const float4*)(ob + (size_t)b*size))[i4];
    int L = i4 << 2;
    int a = L / hw;                 // hw % 4 == 0 -> same a for all 4
    int pix = L - a*hw;
    int j0 = pix*3 + a;
    float vv[4] = {v.x, v.y, v.z, v.w};
    #pragma unroll
    for (int q = 0; q < 4; ++q){
      u32 m = mono32(vv[q]);
      u32 bin = m >> 20;
      int j = j0 + 3*q;
      if (bin > b0v){
        u32 s = atomicAdd(&dn, 1u);
        if (s < (u32)KSEL) dbuf[s] = (u32)j;
      } else if (bin == b0v){
        u32 s = atomicAdd(&tn, 1u);
        if (s < 4096u) tbuf[s] = ((u64)m << 32) | (u32)(~(u32)j);
      }
    }
  }
  __syncthreads();
  if (threadIdx.x == 0){
    dbase = dn ? atomicAdd(&emitcnt[bid16], dn) : 0u;
    tbase = tn ? atomicAdd(&tiecnt[bid16], tn) : 0u;
  }
  __syncthreads();
  for (u32 x = threadIdx.x; x < dn; x += 1024){
    u32 s = dbase + x;
    if (s < (u32)KSEL) cand_j[bid16*KSEL + s] = (int)dbuf[x];
  }
  for (u32 x = threadIdx.x; x < tn; x += 1024){
    u32 s = tbase + x;
    if (s < (u32)EQCAP) gtie[(size_t)bid16*EQCAP + s] = tbuf[x];
  }
}

// ---------------------------------------------------------------------------
// K1d: O(n^2) exact rank-select on the tie set; append k = 512-cntAbove
// winners (LDS-aggregated, one global reservation).
// ---------------------------------------------------------------------------
__global__ __launch_bounds__(1024) void k1d_tie(
    const u64* __restrict__ gtie, const u32* __restrict__ tiecnt,
    const u32* __restrict__ gcA, u32* __restrict__ emitcnt,
    int* __restrict__ cand_j)
{
  int bid = blockIdx.x;               // 16
  __shared__ u64 eq[EQCAP];           // 64 KB
  __shared__ u32 wbuf[KSEL];
  __shared__ u32 wn, wbase;
  u32 n = tiecnt[bid]; if (n > (u32)EQCAP) n = (u32)EQCAP;
  u32 k = (u32)KSEL - gcA[bid];
  if (threadIdx.x == 0) wn = 0;
  for (u32 i = threadIdx.x; i < n; i += 1024) eq[i] = gtie[(size_t)bid*EQCAP + i];
  __syncthreads();
  for (u32 i = threadIdx.x; i < n; i += 1024){
    u64 ki = eq[i];
    u32 r = 0;
    for (u32 m = 0; m < n; ++m) r += (eq[m] > ki) ? 1u : 0u;
    if (r < k){
      u32 s = atomicAdd(&wn, 1u);
      if (s < (u32)KSEL) wbuf[s] = (u32)(~(u32)ki);
    }
  }
  __syncthreads();
  if (threadIdx.x == 0) wbase = wn ? atomicAdd(&emitcnt[bid], wn) : 0u;
  __syncthreads();
  for (u32 x = threadIdx.x; x < wn; x += 1024){
    u32 s = wbase + x;
    if (s < (u32)KSEL) cand_j[bid*KSEL + s] = (int)wbuf[x];
  }
}

// ---------------------------------------------------------------------------
// K2: decode the 8192 selected candidates; build sort keys.
// ---------------------------------------------------------------------------
__global__ __launch_bounds__(256) void k2_decode(
    const float* __restrict__ o0, const float* __restrict__ o1,
    const float* __restrict__ o2, const float* __restrict__ o3,
    const float* __restrict__ d0, const float* __restrict__ d1,
    const float* __restrict__ d2, const float* __restrict__ d3,
    const float* __restrict__ anchors,
    const int* __restrict__ cand_j,
    float* __restrict__ cscore, u32* __restrict__ csmono,
    u64* __restrict__ ctb, float* __restrict__ cbox, u8* __restrict__ cvalid)
{
  int c = blockIdx.x*256 + threadIdx.x;
  if (c >= NB*NCAND) return;
  int pair = c >> 9;          // (b,lvl) pair index
  int b = pair >> 2, lvl = pair & 3;
  int j = cand_j[c];
  int hw = lvl_hw(lvl);
  u32 pix = (u32)j / 3u;
  u32 a = (u32)j - pix*3u;
  const float* ob = (lvl==0)?o0 : (lvl==1)?o1 : (lvl==2)?o2 : o3;
  const float* dl = (lvl==0)?d0 : (lvl==1)?d1 : (lvl==2)?d2 : d3;

  float ov = ob[(size_t)(b*3 + (int)a)*hw + pix];
  size_t dbase = ((size_t)(b*3 + (int)a)*6)*(size_t)hw + pix;
  float dx  = dl[dbase + 0*(size_t)hw];
  float dy  = dl[dbase + 1*(size_t)hw];
  float dw  = dl[dbase + 2*(size_t)hw];
  float dh  = dl[dbase + 3*(size_t)hw];
  float dsn = dl[dbase + 4*(size_t)hw];
  float dcs = dl[dbase + 5*(size_t)hw];
  int tt = lvl_off(lvl) + j;
  const float* an = anchors + ((size_t)b*T_ANCH + tt)*5;
  float ax=an[0], ay=an[1], aw=an[2], ah=an[3], aa=an[4];
  dw = fminf(dw, LOG_MAXF); dh = fminf(dh, LOG_MAXF);
  float cx = ax + dx*aw;
  float cy = ay + dy*ah;
  float w  = aw * expf(dw);
  float h  = ah * expf(dh);
  float ang = aa + atan2f(dsn, dcs);
  double sd = 1.0 / (1.0 + exp(-(double)ov));
  float sc = (float)sd;
  bool valid = (w >= 1e-3f) && (h >= 1e-3f) && (sc >= 0.0f);
  cscore[c] = sc;
  csmono[c] = valid ? mono32(sc) : 0u;        // invalid => -inf (stable-sorted by tb)
  // tiebreak: level asc, obj desc, idx asc  (== reference positional order)
  ctb[c] = ((u64)lvl << 50) | ((u64)(u32)(~mono32(ov)) << 18) | (u64)(u32)j;
  cvalid[c] = valid ? 1 : 0;
  float* bb = cbox + (size_t)c*5;
  bb[0]=cx; bb[1]=cy; bb[2]=w; bb[3]=h; bb[4]=ang;
}

// ---------------------------------------------------------------------------
// K3: per-image exact RANK-SORT scatter (replaces bitonic). Keys strictly
// totally ordered ((mono desc, tb asc), tb unique) => rank is an exact
// permutation, output identical to a stable sort. 32 blocks (4 images x 8
// slices of 256); image keys staged in LDS (24 KB); each thread computes its
// element's rank via a 2048-scan (LDS broadcast), then scatters
// score/box/valid/geom/aabb to dst = rank. No barriers in the scan.
// ---------------------------------------------------------------------------
__global__ __launch_bounds__(256) void k3_rank(
    const u32* __restrict__ csmono, const u64* __restrict__ ctb,
    const float* __restrict__ cscore, const float* __restrict__ cbox,
    const u8* __restrict__ cvalid,
    float* __restrict__ sscore, float* __restrict__ sbox,
    float* __restrict__ geom, float4* __restrict__ aabb4,
    u8* __restrict__ svalid)
{
  int b = blockIdx.x >> 3;
  int slice = blockIdx.x & 7;
  __shared__ u32 sm[NCAND];
  __shared__ u64 stb[NCAND];
  for (int k = threadIdx.x; k < NCAND; k += 256){
    sm[k]  = csmono[b*NCAND + k];
    stb[k] = ctb[b*NCAND + k];
  }
  __syncthreads();
  int id = slice*256 + threadIdx.x;
  u32 ms = sm[id];
  u64 mt = stb[id];
  u32 r = 0;
  for (int m = 0; m < NCAND; ++m){
    u32 s2 = sm[m]; u64 t2 = stb[m];
    r += ((s2 > ms) || (s2 == ms && t2 < mt)) ? 1u : 0u;
  }
  int gsrc = b*NCAND + id;
  int gdst = b*NCAND + (int)r;
  sscore[gdst] = cscore[gsrc];
  svalid[gdst] = cvalid[gsrc];
  float b0 = cbox[(size_t)gsrc*5+0], b1 = cbox[(size_t)gsrc*5+1];
  float b2 = cbox[(size_t)gsrc*5+2], b3 = cbox[(size_t)gsrc*5+3];
  float b4 = cbox[(size_t)gsrc*5+4];
  float* sb = sbox + (size_t)gdst*5;
  sb[0]=b0; sb[1]=b1; sb[2]=b2; sb[3]=b3; sb[4]=b4;
  int lvl = (int)((mt >> 50) & 3ull);
  float offv = (float)lvl * LVL_OFF_F;
  float cx = b0 + offv, cy = b1 + offv, w=b2, h=b3, ang=b4;
  float cc = cosf(ang), sn = sinf(ang);
  float hx = 0.5f*w, hy = 0.5f*h;
  float x0 = cx + hx*cc - hy*sn, y0 = cy + hx*sn + hy*cc;
  float x1 = cx - hx*cc - hy*sn, y1 = cy - hx*sn + hy*cc;
  float x2 = cx - hx*cc + hy*sn, y2 = cy - hx*sn - hy*cc;
  float x3 = cx + hx*cc + hy*sn, y3 = cy + hx*sn - hy*cc;
  float minx = fminf(fminf(x0,x1),fminf(x2,x3));
  float maxx = fmaxf(fmaxf(x0,x1),fmaxf(x2,x3));
  float miny = fminf(fminf(y0,y1),fminf(y2,y3));
  float maxy = fmaxf(fmaxf(y0,y1),fmaxf(y2,y3));
  float* g = geom + (size_t)gdst*16;
  g[0]=minx; g[1]=maxx; g[2]=miny; g[3]=maxy; g[4]=w*h;
  g[5]=x0; g[6]=y0; g[7]=x1; g[8]=y1; g[9]=x2; g[10]=y2; g[11]=x3; g[12]=y3;
  aabb4[gdst] = make_float4(minx, maxx, miny, maxy);
}

// ---------------------------------------------------------------------------
// K4a: AABB filter -> compacted pair list (packed aabb4, 32 KB LDS list,
// one global atomicAdd per block). See R10 notes.
// ---------------------------------------------------------------------------
__global__ __launch_bounds__(256) void k4a_aabb(
    const float4* __restrict__ aabb4,
    u32* __restrict__ list, u32* __restrict__ gcount)
{
  __shared__ u32 lbuf[K4A_ROWS*NCAND];   // 32 KB
  __shared__ u32 lcnt, lbase;
  if (threadIdx.x == 0) lcnt = 0;
  __syncthreads();
  int img = blockIdx.x >> 9;               // 512 blocks per image
  int i0  = (blockIdx.x & 511) * K4A_ROWS;
  #pragma unroll
  for (int r = 0; r < K4A_ROWS; ++r){
    int i = i0 + r;
    float4 gi = aabb4[img*NCAND + i];      // uniform -> cache broadcast
    for (int j = threadIdx.x; j < NCAND; j += 256){
      bool pass = false;
      if (j > i){
        float4 gj = aabb4[img*NCAND + j];
        pass = !(gi.x > gj.y || gj.x > gi.y || gi.z > gj.w || gj.z > gi.w);
      }
      if (pass){
        u32 s = atomicAdd(&lcnt, 1u);
        lbuf[s] = (u32)((img << 22) | (i << 11) | j);
      }
    }
  }
  __syncthreads();
  if (threadIdx.x == 0) lbase = lcnt ? atomicAdd(gcount, lcnt) : 0u;
  __syncthreads();
  u32 n = lcnt, bs = lbase;
  for (u32 x = threadIdx.x; x < n; x += 256){
    u32 idx = bs + x;
    if (idx < PAIR_CAP) list[idx] = lbuf[x];
  }
}

// ---------------------------------------------------------------------------
// K4b: dense clip over the compacted list; scatter bits via atomicOr.
// ---------------------------------------------------------------------------
__device__ __forceinline__ void emit_pt(float* ox, float* oy, int oc, float x, float y){
  #pragma unroll
  for (int s = 0; s < 8; ++s) if (s == oc){ ox[s] = x; oy[s] = y; }
}

__device__ float quad_inter(const float* ca, const float* cb){
  float px[8], py[8];
  #pragma unroll
  for (int q = 0; q < 8; ++q){ px[q]=0.f; py[q]=0.f; }
  #pragma unroll
  for (int q = 0; q < 4; ++q){ px[q]=ca[2*q]; py[q]=ca[2*q+1]; }
  int cnt = 4;
  #pragma unroll
  for (int e = 0; e < 4; ++e){
    float p1x = cb[2*e],         p1y = cb[2*e+1];
    float p2x = cb[(2*e+2)&7],   p2y = cb[(2*e+3)&7];
    float ex = p2x-p1x, ey = p2y-p1y;
    float d[8];
    #pragma unroll
    for (int q = 0; q < 8; ++q) d[q] = ex*(py[q]-p1y) - ey*(px[q]-p1x);
    float ox[8], oy[8];
    #pragma unroll
    for (int q = 0; q < 8; ++q){ ox[q]=0.f; oy[q]=0.f; }
    int oc = 0;
    #pragma unroll
    for (int q = 0; q < 8; ++q){
      if (q < cnt){
        bool last = (q+1 >= cnt);
        float dn  = last ? d[0]  : d[(q+1)&7];
        bool in0 = (d[q] >= 0.0f), in1 = (dn >= 0.0f);
        if (in0){ emit_pt(ox,oy,oc,px[q],py[q]); oc++; }
        if (in0 != in1){
          float pnx = last ? px[0] : px[(q+1)&7];
          float pny = last ? py[0] : py[(q+1)&7];
          float den = d[q] - dn;
          float t = d[q] / ((den == 0.0f) ? 1.0f : den);
          emit_pt(ox,oy,oc, px[q] + t*(pnx-px[q]), py[q] + t*(pny-py[q]));
          oc++;
        }
      }
    }
    cnt = (oc > 8) ? 8 : oc;
    #pragma unroll
    for (int q = 0; q < 8; ++q){ px[q]=ox[q]; py[q]=oy[q]; }
  }
  if (cnt < 3) return 0.0f;
  float s = 0.0f;
  #pragma unroll
  for (int q = 0; q < 8; ++q){
    if (q < cnt){
      bool last = (q+1 >= cnt);
      float pnx = last ? px[0] : px[(q+1)&7];
      float pny = last ? py[0] : py[(q+1)&7];
      s += px[q]*pny - pnx*py[q];
    }
  }
  return 0.5f*fabsf(s);
}

__global__ __launch_bounds__(256) void k4b_clip(
    const float* __restrict__ geom, const u32* __restrict__ list,
    const u32* __restrict__ gcount, u64* __restrict__ mask)
{
  u32 count = *gcount;
  if (count > PAIR_CAP) count = PAIR_CAP;
  for (u32 idx = blockIdx.x*256 + threadIdx.x; idx < count; idx += gridDim.x*256){
    u32 gt = list[idx];
    int img = (int)(gt >> 22);
    int rem = (int)(gt & ((1u<<22)-1));
    int i = rem >> 11;
    int j = rem & (NCAND-1);
    const float* gi = geom + ((size_t)(img*NCAND + i))*16;
    const float* gj = geom + ((size_t)(img*NCAND + j))*16;
    float inter = quad_inter(gi+5, gj+5);
    float iou = inter / (gi[4] + gj[4] - inter + 1e-7f);
    if (iou > NMS_TH)
      atomicOr(&mask[((size_t)(img*NCAND + i))*32 + (j >> 6)], 1ull << (j & 63));
  }
}

// ---------------------------------------------------------------------------
// K5: sequential greedy suppression, sup in wave-0 registers, early exit at
// the 512th kept row (see R6 notes).
// ---------------------------------------------------------------------------
__global__ __launch_bounds__(1024) void k5_nms_out(
    const u64* __restrict__ mask, const u8* __restrict__ svalid,
    const float* __restrict__ sbox, const float* __restrict__ sscore,
    float* __restrict__ out)
{
  int b = blockIdx.x;
  __shared__ u64 buf[2][128*32];      // 64 KB double buffer
  __shared__ u64 s_kept[32];
  __shared__ u32 pref[32];
  __shared__ u32 s_done, s_R;
  int t = threadIdx.x;
  int wid = t >> 6, lane = t & 63;

  if (t == 0){ s_done = 0; s_R = NCAND - 1; }

  // sup init from svalid: lane l (l<32) builds word l; lanes 32-63 mirror.
  u32 slo = 0, shi = 0;
  if (wid == 0){
    int wl = lane & 31;
    u64 w = 0;
    for (int q = 0; q < 64; ++q)
      if (!svalid[b*NCAND + wl*64 + q]) w |= (1ull << q);
    slo = (u32)w; shi = (u32)(w >> 32);
  }
  // preload chunk 0 (all waves)
  {
    const u64* src = mask + ((size_t)b*NCAND)*32;
    for (int x = t; x < 128*32; x += 1024) buf[0][x] = src[x];
  }
  __syncthreads();

  u32 kcnt = 0;
  bool stopped = false;
  for (int c = 0; c < 16; ++c){
    if (wid != 0){
      if (c + 1 < 16){
        const u64* src = mask + ((size_t)(b*NCAND + (c+1)*128))*32;
        for (int x = t - 64; x < 128*32; x += (1024 - 64))
          buf[(c+1)&1][x] = src[x];
      }
    } else if (!stopped){
      const u64* ch = buf[c&1];
      for (int r8 = 0; r8 < 128 && !stopped; r8 += 8){
        u64 v[8];
        #pragma unroll
        for (int q = 0; q < 8; ++q) v[q] = ch[(r8+q)*32 + (lane & 31)];
        #pragma unroll
        for (int q = 0; q < 8; ++q){
          int gi = c*128 + r8 + q;
          int wi = gi >> 6;                       // wave-uniform
          u32 wlo = (u32)__builtin_amdgcn_readlane((int)slo, wi);
          u32 whi = (u32)__builtin_amdgcn_readlane((int)shi, wi);
          u64 w = ((u64)whi << 32) | wlo;
          u32 keep = (u32)((~w >> (gi & 63)) & 1ull);
          u64 vm = v[q] & (0ull - (u64)keep);     // branchless: keep ? v : 0
          slo |= (u32)vm; shi |= (u32)(vm >> 32);
          kcnt += keep;
          if (kcnt >= (u32)POSTN){                // 512th keep -> stop
            if (lane == 0){ s_done = 1; s_R = (u32)gi; }
            stopped = true;
            break;
          }
        }
      }
    }
    __syncthreads();
    if (s_done) break;
    __syncthreads();
  }
  // publish kept words, range-masked to rows <= R
  if (wid == 0 && lane < 32){
    u32 Rv = s_R;
    int lo_row = (int)lane * 64;
    u64 sup = ((u64)shi << 32) | slo;
    u64 rmask;
    if (lo_row + 63 <= (int)Rv) rmask = ~0ull;
    else if (lo_row > (int)Rv)  rmask = 0ull;
    else                        rmask = (1ull << ((int)Rv - lo_row + 1)) - 1ull;
    s_kept[lane] = (~sup) & rmask;
  }
  __syncthreads();

  // zero-fill this image's output (d_out is poisoned before every launch)
  for (int x = t; x < POSTN*5; x += 1024) out[(size_t)b*POSTN*5 + x] = 0.0f;
  for (int x = t; x < POSTN;   x += 1024) out[(size_t)NB*POSTN*5 + b*POSTN + x] = 0.0f;
  if (t < 32) pref[t] = (u32)__popcll(s_kept[t]);
  __syncthreads();
  if (t == 0){
    u32 run = 0;
    for (int w = 0; w < 32; ++w){ u32 tv = pref[w]; pref[w] = run; run += tv; }
  }
  __syncthreads();
  for (int i = t; i < NCAND; i += 1024){
    u64 kw = s_kept[i >> 6];
    if ((kw >> (i & 63)) & 1ull){
      u32 rank = pref[i >> 6] + (u32)__popcll(kw & ((1ull << (i & 63)) - 1ull));
      if (rank < POSTN){
        const float* bp = sbox + ((size_t)(b*NCAND + i))*5;
        float* op = out + ((size_t)(b*POSTN + rank))*5;
        op[0]=bp[0]; op[1]=bp[1]; op[2]=bp[2]; op[3]=bp[3]; op[4]=bp[4];
        out[(size_t)NB*POSTN*5 + b*POSTN + rank] = sscore[b*NCAND + i];
      }
    }
  }
}

// ---------------------------------------------------------------------------
extern "C" void kernel_launch(void* const* d_in, const int* in_sizes, int n_in,
                              void* d_out, int out_size, void* d_ws, size_t ws_size,
                              hipStream_t stream)
{
  (void)out_size; (void)ws_size;
  const float *obj[4] = {nullptr,nullptr,nullptr,nullptr};
  const float *dlt[4] = {nullptr,nullptr,nullptr,nullptr};
  const float *anchors = nullptr;
  for (int i = 0; i < n_in; ++i){
    int s = in_sizes[i];
    const float* p = (const float*)d_in[i];
    switch (s){
      case 786432:  obj[0] = p; break;
      case 4718592: dlt[0] = p; break;
      case 196608:  obj[1] = p; break;
      case 1179648: dlt[1] = p; break;
      case 49152:   obj[2] = p; break;
      case 294912:  dlt[2] = p; break;
      case 12288:   obj[3] = p; break;
      case 73728:   dlt[3] = p; break;
      case 5222400: anchors = p; break;
      default: break;
    }
  }

  char* wsb = (char*)d_ws;
  size_t off = 0;
  auto alloc = [&](size_t bytes)->void*{
    size_t cur = (off + 255) & ~(size_t)255;
    off = cur + bytes;
    return (void*)(wsb + cur);
  };
  int*   cand_j = (int*)  alloc(16*KSEL*sizeof(int));
  float* cscore = (float*)alloc((size_t)NB*NCAND*sizeof(float));
  u32*   csmono = (u32*)  alloc((size_t)NB*NCAND*sizeof(u32));
  u64*   ctb    = (u64*)  alloc((size_t)NB*NCAND*sizeof(u64));
  float* cbox   = (float*)alloc((size_t)NB*NCAND*5*sizeof(float));
  u8*    cvalid = (u8*)   alloc((size_t)NB*NCAND);
  float* sscore = (float*)alloc((size_t)NB*NCAND*sizeof(float));
  float* sbox   = (float*)alloc((size_t)NB*NCAND*5*sizeof(float));
  u8*    svalid = (u8*)   alloc((size_t)NB*NCAND);
  float* geom   = (float*)alloc((size_t)NB*NCAND*16*sizeof(float));
  float4* aabb4 = (float4*)alloc((size_t)NB*NCAND*sizeof(float4));
  u64*   maskp  = (u64*)  alloc((size_t)NB*NCAND*32*sizeof(u64));
  u32*   plist  = (u32*)  alloc((size_t)PAIR_CAP*sizeof(u32));
  u32*   pcount = (u32*)  alloc(sizeof(u32));
  u32*   ghist  = (u32*)  alloc((size_t)K1_BLOCKS*BINS*sizeof(u32));
  u64*   gtie   = (u64*)  alloc((size_t)16*EQCAP*sizeof(u64));
  u32*   gb0    = (u32*)  alloc(16*sizeof(u32));
  u32*   gcA    = (u32*)  alloc(16*sizeof(u32));
  u32*   emitc  = (u32*)  alloc(16*sizeof(u32));
  u32*   tiec   = (u32*)  alloc(16*sizeof(u32));

  hipMemsetAsync(pcount, 0, sizeof(u32), stream);
  hipMemsetAsync(maskp, 0, (size_t)NB*NCAND*32*sizeof(u64), stream);

  hipLaunchKernelGGL(k1a_hist, dim3(K1_BLOCKS), dim3(1024), 0, stream,
                     obj[0], obj[1], obj[2], obj[3], ghist);
  hipLaunchKernelGGL(k1b_thresh, dim3(16), dim3(1024), 0, stream,
                     ghist, gb0, gcA, emitc, tiec);
  hipLaunchKernelGGL(k1c_classify, dim3(K1_BLOCKS), dim3(1024), 0, stream,
                     obj[0], obj[1], obj[2], obj[3], gb0, emitc, tiec,
                     cand_j, gtie);
  hipLaunchKernelGGL(k1d_tie, dim3(16), dim3(1024), 0, stream,
                     gtie, tiec, gcA, emitc, cand_j);
  hipLaunchKernelGGL(k2_decode, dim3(32), dim3(256), 0, stream,
                     obj[0], obj[1], obj[2], obj[3],
                     dlt[0], dlt[1], dlt[2], dlt[3],
                     anchors, cand_j, cscore, csmono, ctb, cbox, cvalid);
  hipLaunchKernelGGL(k3_rank, dim3(32), dim3(256), 0, stream,
                     csmono, ctb, cscore, cbox, cvalid, sscore, sbox, geom,
                     aabb4, svalid);
  hipLaunchKernelGGL(k4a_aabb, dim3(K4A_BLOCKS), dim3(256), 0, stream,
                     aabb4, plist, pcount);
  hipLaunchKernelGGL(k4b_clip, dim3(256), dim3(256), 0, stream,
                     geom, plist, pcount, maskp);
  hipLaunchKernelGGL(k5_nms_out, dim3(4), dim3(1024), 0, stream,
                     maskp, svalid, sbox, sscore, (float*)d_out);
}

// Round 12
// 246.638 us; speedup vs baseline: 1.6164x; 1.6164x over previous
//
#include <hip/hip_runtime.h>

typedef unsigned int u32;
typedef unsigned long long u64;
typedef unsigned char u8;

#define NB 4
#define T_ANCH 261120
#define NCAND 2048          // candidates per image (4 levels x 512)
#define KSEL 512
#define POSTN 512
#define LOG_MAXF 4.135166556742356f
#define NMS_TH 0.7f
#define LVL_OFF_F 8192.0f
#define BINS 4096           // top-12 bits of mono32
#define EQCAP 8192          // tie-bin capacity (expected ~300-700 occupants)
#define PAIR_CAP (1u<<20)   // 1M compacted pairs
#define K4A_BLOCKS 2048     // 4 i-rows (8192 pairs) per block -> 32 KB LDS
#define K4A_ROWS 4
#define K1_BLOCKS 256       // 64 chunk-blocks per image (48/12/3/1 per level)

__device__ __forceinline__ u32 mono32(float f){
  u32 u = __float_as_uint(f);
  return (u & 0x80000000u) ? ~u : (u | 0x80000000u);
}
__device__ __forceinline__ int lvl_hw(int lvl){ return 65536 >> (2*lvl); }
__device__ __forceinline__ int lvl_off(int lvl){
  return (lvl>0?196608:0) + (lvl>1?49152:0) + (lvl>2?12288:0);
}
// chunk-block mapping: bx in [0,256): b = bx>>6, c = bx&63
__device__ __forceinline__ void k1_map(int bx, int& b, int& lvl, int& ch){
  b = bx >> 6;
  int c = bx & 63;
  if (c < 48){ lvl = 0; ch = c; }
  else if (c < 60){ lvl = 1; ch = c - 48; }
  else if (c < 63){ lvl = 2; ch = c - 60; }
  else { lvl = 3; ch = 0; }
}

// ---------------------------------------------------------------------------
// K1a: per-chunk private histogram of mono32>>20. 256 blocks, 1 float4/thread.
// ---------------------------------------------------------------------------
__global__ __launch_bounds__(1024) void k1a_hist(
    const float* __restrict__ o0, const float* __restrict__ o1,
    const float* __restrict__ o2, const float* __restrict__ o3,
    u32* __restrict__ ghist)
{
  int b, lvl, ch;
  k1_map(blockIdx.x, b, lvl, ch);
  const float* ob = (lvl==0)?o0 : (lvl==1)?o1 : (lvl==2)?o2 : o3;
  int hw = lvl_hw(lvl);
  int size = 3*hw;
  int n4 = size >> 2;
  int i4 = ch*1024 + threadIdx.x;
  __shared__ u32 hist[BINS];
  for (int i = threadIdx.x; i < BINS; i += 1024) hist[i] = 0;
  __syncthreads();
  if (i4 < n4){
    float4 v = ((const float4*)(ob + (size_t)b*size))[i4];
    atomicAdd(&hist[mono32(v.x) >> 20], 1u);
    atomicAdd(&hist[mono32(v.y) >> 20], 1u);
    atomicAdd(&hist[mono32(v.z) >> 20], 1u);
    atomicAdd(&hist[mono32(v.w) >> 20], 1u);
  }
  __syncthreads();
  u32* out = ghist + (size_t)blockIdx.x*BINS;
  for (int i = threadIdx.x; i < BINS; i += 1024) out[i] = hist[i];
}

// ---------------------------------------------------------------------------
// K1b: reduce chunk histograms per (b,lvl); serial threshold walk -> b0,
// cntAbove; zero emit/tie counters.
// ---------------------------------------------------------------------------
__global__ __launch_bounds__(1024) void k1b_thresh(
    const u32* __restrict__ ghist, u32* __restrict__ gb0,
    u32* __restrict__ gcA, u32* __restrict__ emitcnt, u32* __restrict__ tiecnt)
{
  int bid = blockIdx.x;               // 16 = (b,lvl)
  int b = bid >> 2, lvl = bid & 3;
  int base_bx = b*64 + (lvl==0?0 : lvl==1?48 : lvl==2?60 : 63);
  int nch = (lvl==0?48 : lvl==1?12 : lvl==2?3 : 1);
  __shared__ u32 hist[BINS];
  __shared__ u32 coarse[64];
  int t = threadIdx.x;
  u32 c0=0,c1=0,c2=0,c3=0;
  for (int ch = 0; ch < nch; ++ch){
    const u32* h = ghist + (size_t)(base_bx+ch)*BINS;
    c0 += h[4*t+0]; c1 += h[4*t+1]; c2 += h[4*t+2]; c3 += h[4*t+3];
  }
  hist[4*t+0]=c0; hist[4*t+1]=c1; hist[4*t+2]=c2; hist[4*t+3]=c3;
  __syncthreads();
  if (t < 64){
    u32 s = 0;
    for (int z = 0; z < 64; ++z) s += hist[t*64 + z];
    coarse[t] = s;
  }
  __syncthreads();
  if (t == 0){
    u32 acc = 0;
    int cb = 63;
    while (acc + coarse[cb] < (u32)KSEL){ acc += coarse[cb]; --cb; }
    int z = cb*64 + 63;
    while (acc + hist[z] < (u32)KSEL){ acc += hist[z]; --z; }
    gb0[bid] = (u32)z;
    gcA[bid] = acc;
    emitcnt[bid] = 0;
    tiecnt[bid] = 0;
  }
}

// ---------------------------------------------------------------------------
// K1c: classify chunk elements vs b0. LDS lists + ONE global reservation per
// list per block. Emits PERMUTED index j = pix*3 + a (see R4 notes).
// ---------------------------------------------------------------------------
__global__ __launch_bounds__(1024) void k1c_classify(
    const float* __restrict__ o0, const float* __restrict__ o1,
    const float* __restrict__ o2, const float* __restrict__ o3,
    const u32* __restrict__ gb0,
    u32* __restrict__ emitcnt, u32* __restrict__ tiecnt,
    int* __restrict__ cand_j, u64* __restrict__ gtie)
{
  int b, lvl, ch;
  k1_map(blockIdx.x, b, lvl, ch);
  int bid16 = b*4 + lvl;
  const float* ob = (lvl==0)?o0 : (lvl==1)?o1 : (lvl==2)?o2 : o3;
  int hw = lvl_hw(lvl);
  int size = 3*hw;
  int n4 = size >> 2;
  int i4 = ch*1024 + threadIdx.x;

  __shared__ u32 dbuf[KSEL];
  __shared__ u64 tbuf[4096];
  __shared__ u32 dn, tn, dbase, tbase;
  if (threadIdx.x == 0){ dn = 0; tn = 0; }
  __syncthreads();

  u32 b0v = gb0[bid16];
  if (i4 < n4){
    float4 v = ((const float4*)(ob + (size_t)b*size))[i4];
    int L = i4 << 2;
    int a = L / hw;                 // hw % 4 == 0 -> same a for all 4
    int pix = L - a*hw;
    int j0 = pix*3 + a;
    float vv[4] = {v.x, v.y, v.z, v.w};
    #pragma unroll
    for (int q = 0; q < 4; ++q){
      u32 m = mono32(vv[q]);
      u32 bin = m >> 20;
      int j = j0 + 3*q;
      if (bin > b0v){
        u32 s = atomicAdd(&dn, 1u);
        if (s < (u32)KSEL) dbuf[s] = (u32)j;
      } else if (bin == b0v){
        u32 s = atomicAdd(&tn, 1u);
        if (s < 4096u) tbuf[s] = ((u64)m << 32) | (u32)(~(u32)j);
      }
    }
  }
  __syncthreads();
  if (threadIdx.x == 0){
    dbase = dn ? atomicAdd(&emitcnt[bid16], dn) : 0u;
    tbase = tn ? atomicAdd(&tiecnt[bid16], tn) : 0u;
  }
  __syncthreads();
  for (u32 x = threadIdx.x; x < dn; x += 1024){
    u32 s = dbase + x;
    if (s < (u32)KSEL) cand_j[bid16*KSEL + s] = (int)dbuf[x];
  }
  for (u32 x = threadIdx.x; x < tn; x += 1024){
    u32 s = tbase + x;
    if (s < (u32)EQCAP) gtie[(size_t)bid16*EQCAP + s] = tbuf[x];
  }
}

// ---------------------------------------------------------------------------
// K1d: O(n^2) exact rank-select on the tie set; append k = 512-cntAbove
// winners (LDS-aggregated, one global reservation).
// ---------------------------------------------------------------------------
__global__ __launch_bounds__(1024) void k1d_tie(
    const u64* __restrict__ gtie, const u32* __restrict__ tiecnt,
    const u32* __restrict__ gcA, u32* __restrict__ emitcnt,
    int* __restrict__ cand_j)
{
  int bid = blockIdx.x;               // 16
  __shared__ u64 eq[EQCAP];           // 64 KB
  __shared__ u32 wbuf[KSEL];
  __shared__ u32 wn, wbase;
  u32 n = tiecnt[bid]; if (n > (u32)EQCAP) n = (u32)EQCAP;
  u32 k = (u32)KSEL - gcA[bid];
  if (threadIdx.x == 0) wn = 0;
  for (u32 i = threadIdx.x; i < n; i += 1024) eq[i] = gtie[(size_t)bid*EQCAP + i];
  __syncthreads();
  for (u32 i = threadIdx.x; i < n; i += 1024){
    u64 ki = eq[i];
    u32 r = 0;
    for (u32 m = 0; m < n; ++m) r += (eq[m] > ki) ? 1u : 0u;
    if (r < k){
      u32 s = atomicAdd(&wn, 1u);
      if (s < (u32)KSEL) wbuf[s] = (u32)(~(u32)ki);
    }
  }
  __syncthreads();
  if (threadIdx.x == 0) wbase = wn ? atomicAdd(&emitcnt[bid], wn) : 0u;
  __syncthreads();
  for (u32 x = threadIdx.x; x < wn; x += 1024){
    u32 s = wbase + x;
    if (s < (u32)KSEL) cand_j[bid*KSEL + s] = (int)wbuf[x];
  }
}

// ---------------------------------------------------------------------------
// K2: decode the 8192 selected candidates; build sort keys.
// ---------------------------------------------------------------------------
__global__ __launch_bounds__(256) void k2_decode(
    const float* __restrict__ o0, const float* __restrict__ o1,
    const float* __restrict__ o2, const float* __restrict__ o3,
    const float* __restrict__ d0, const float* __restrict__ d1,
    const float* __restrict__ d2, const float* __restrict__ d3,
    const float* __restrict__ anchors,
    const int* __restrict__ cand_j,
    float* __restrict__ cscore, u32* __restrict__ csmono,
    u64* __restrict__ ctb, float* __restrict__ cbox, u8* __restrict__ cvalid)
{
  int c = blockIdx.x*256 + threadIdx.x;
  if (c >= NB*NCAND) return;
  int pair = c >> 9;          // (b,lvl) pair index
  int b = pair >> 2, lvl = pair & 3;
  int j = cand_j[c];
  int hw = lvl_hw(lvl);
  u32 pix = (u32)j / 3u;
  u32 a = (u32)j - pix*3u;
  const float* ob = (lvl==0)?o0 : (lvl==1)?o1 : (lvl==2)?o2 : o3;
  const float* dl = (lvl==0)?d0 : (lvl==1)?d1 : (lvl==2)?d2 : d3;

  float ov = ob[(size_t)(b*3 + (int)a)*hw + pix];
  size_t dbase = ((size_t)(b*3 + (int)a)*6)*(size_t)hw + pix;
  float dx  = dl[dbase + 0*(size_t)hw];
  float dy  = dl[dbase + 1*(size_t)hw];
  float dw  = dl[dbase + 2*(size_t)hw];
  float dh  = dl[dbase + 3*(size_t)hw];
  float dsn = dl[dbase + 4*(size_t)hw];
  float dcs = dl[dbase + 5*(size_t)hw];
  int tt = lvl_off(lvl) + j;
  const float* an = anchors + ((size_t)b*T_ANCH + tt)*5;
  float ax=an[0], ay=an[1], aw=an[2], ah=an[3], aa=an[4];
  dw = fminf(dw, LOG_MAXF); dh = fminf(dh, LOG_MAXF);
  float cx = ax + dx*aw;
  float cy = ay + dy*ah;
  float w  = aw * expf(dw);
  float h  = ah * expf(dh);
  float ang = aa + atan2f(dsn, dcs);
  double sd = 1.0 / (1.0 + exp(-(double)ov));
  float sc = (float)sd;
  bool valid = (w >= 1e-3f) && (h >= 1e-3f) && (sc >= 0.0f);
  cscore[c] = sc;
  csmono[c] = valid ? mono32(sc) : 0u;        // invalid => -inf (stable-sorted by tb)
  // tiebreak: level asc, obj desc, idx asc  (== reference positional order)
  ctb[c] = ((u64)lvl << 50) | ((u64)(u32)(~mono32(ov)) << 18) | (u64)(u32)j;
  cvalid[c] = valid ? 1 : 0;
  float* bb = cbox + (size_t)c*5;
  bb[0]=cx; bb[1]=cy; bb[2]=w; bb[3]=h; bb[4]=ang;
}

// ---------------------------------------------------------------------------
// K3: per-image exact RANK-SORT scatter, parallelized over 256 blocks
// (4 images x 64 blocks; 32 elements per block; 8 scan-threads per element,
// each scanning m = it*8 + s so a wave's 8 distinct LDS addresses fall in
// consecutive banks). Keys strictly totally ordered => rank is an exact
// permutation (output identical to a stable sort). Thread s==0 of each
// element sums the 8 partials and does geometry + scatter to dst = rank.
// ---------------------------------------------------------------------------
__global__ __launch_bounds__(256) void k3_rank(
    const u32* __restrict__ csmono, const u64* __restrict__ ctb,
    const float* __restrict__ cscore, const float* __restrict__ cbox,
    const u8* __restrict__ cvalid,
    float* __restrict__ sscore, float* __restrict__ sbox,
    float* __restrict__ geom, float4* __restrict__ aabb4,
    u8* __restrict__ svalid)
{
  int b   = blockIdx.x >> 6;          // image
  int blk = blockIdx.x & 63;          // 64 blocks per image, 32 elems each
  __shared__ u32 sm[NCAND];
  __shared__ u64 stb[NCAND];
  __shared__ u32 cnt[32][8];
  for (int k = threadIdx.x; k < NCAND; k += 256){
    sm[k]  = csmono[b*NCAND + k];
    stb[k] = ctb[b*NCAND + k];
  }
  __syncthreads();
  int esub = threadIdx.x >> 3;        // 0..31 element within block
  int ssub = threadIdx.x & 7;         // 0..7 scan slice
  int id = blk*32 + esub;
  u32 ms = sm[id];
  u64 mt = stb[id];
  u32 r = 0;
  #pragma unroll 8
  for (int it = 0; it < 256; ++it){
    int m = it*8 + ssub;
    u32 s2 = sm[m]; u64 t2 = stb[m];
    r += ((s2 > ms) || (s2 == ms && t2 < mt)) ? 1u : 0u;
  }
  cnt[esub][ssub] = r;
  __syncthreads();
  if (ssub == 0){
    u32 rank = 0;
    #pragma unroll
    for (int q = 0; q < 8; ++q) rank += cnt[esub][q];
    int gsrc = b*NCAND + id;
    int gdst = b*NCAND + (int)rank;
    sscore[gdst] = cscore[gsrc];
    svalid[gdst] = cvalid[gsrc];
    float b0 = cbox[(size_t)gsrc*5+0], b1 = cbox[(size_t)gsrc*5+1];
    float b2 = cbox[(size_t)gsrc*5+2], b3 = cbox[(size_t)gsrc*5+3];
    float b4 = cbox[(size_t)gsrc*5+4];
    float* sb = sbox + (size_t)gdst*5;
    sb[0]=b0; sb[1]=b1; sb[2]=b2; sb[3]=b3; sb[4]=b4;
    int lvl = (int)((mt >> 50) & 3ull);
    float offv = (float)lvl * LVL_OFF_F;
    float cx = b0 + offv, cy = b1 + offv, w=b2, h=b3, ang=b4;
    float cc = cosf(ang), sn = sinf(ang);
    float hx = 0.5f*w, hy = 0.5f*h;
    float x0 = cx + hx*cc - hy*sn, y0 = cy + hx*sn + hy*cc;
    float x1 = cx - hx*cc - hy*sn, y1 = cy - hx*sn + hy*cc;
    float x2 = cx - hx*cc + hy*sn, y2 = cy - hx*sn - hy*cc;
    float x3 = cx + hx*cc + hy*sn, y3 = cy + hx*sn - hy*cc;
    float minx = fminf(fminf(x0,x1),fminf(x2,x3));
    float maxx = fmaxf(fmaxf(x0,x1),fmaxf(x2,x3));
    float miny = fminf(fminf(y0,y1),fminf(y2,y3));
    float maxy = fmaxf(fmaxf(y0,y1),fmaxf(y2,y3));
    float* g = geom + (size_t)gdst*16;
    g[0]=minx; g[1]=maxx; g[2]=miny; g[3]=maxy; g[4]=w*h;
    g[5]=x0; g[6]=y0; g[7]=x1; g[8]=y1; g[9]=x2; g[10]=y2; g[11]=x3; g[12]=y3;
    aabb4[gdst] = make_float4(minx, maxx, miny, maxy);
  }
}

// ---------------------------------------------------------------------------
// K4a: AABB filter -> compacted pair list (packed aabb4, 32 KB LDS list,
// one global atomicAdd per block). See R10 notes.
// ---------------------------------------------------------------------------
__global__ __launch_bounds__(256) void k4a_aabb(
    const float4* __restrict__ aabb4,
    u32* __restrict__ list, u32* __restrict__ gcount)
{
  __shared__ u32 lbuf[K4A_ROWS*NCAND];   // 32 KB
  __shared__ u32 lcnt, lbase;
  if (threadIdx.x == 0) lcnt = 0;
  __syncthreads();
  int img = blockIdx.x >> 9;               // 512 blocks per image
  int i0  = (blockIdx.x & 511) * K4A_ROWS;
  #pragma unroll
  for (int r = 0; r < K4A_ROWS; ++r){
    int i = i0 + r;
    float4 gi = aabb4[img*NCAND + i];      // uniform -> cache broadcast
    for (int j = threadIdx.x; j < NCAND; j += 256){
      bool pass = false;
      if (j > i){
        float4 gj = aabb4[img*NCAND + j];
        pass = !(gi.x > gj.y || gj.x > gi.y || gi.z > gj.w || gj.z > gi.w);
      }
      if (pass){
        u32 s = atomicAdd(&lcnt, 1u);
        lbuf[s] = (u32)((img << 22) | (i << 11) | j);
      }
    }
  }
  __syncthreads();
  if (threadIdx.x == 0) lbase = lcnt ? atomicAdd(gcount, lcnt) : 0u;
  __syncthreads();
  u32 n = lcnt, bs = lbase;
  for (u32 x = threadIdx.x; x < n; x += 256){
    u32 idx = bs + x;
    if (idx < PAIR_CAP) list[idx] = lbuf[x];
  }
}

// ---------------------------------------------------------------------------
// K4b: dense clip over the compacted list; scatter bits via atomicOr.
// ---------------------------------------------------------------------------
__device__ __forceinline__ void emit_pt(float* ox, float* oy, int oc, float x, float y){
  #pragma unroll
  for (int s = 0; s < 8; ++s) if (s == oc){ ox[s] = x; oy[s] = y; }
}

__device__ float quad_inter(const float* ca, const float* cb){
  float px[8], py[8];
  #pragma unroll
  for (int q = 0; q < 8; ++q){ px[q]=0.f; py[q]=0.f; }
  #pragma unroll
  for (int q = 0; q < 4; ++q){ px[q]=ca[2*q]; py[q]=ca[2*q+1]; }
  int cnt = 4;
  #pragma unroll
  for (int e = 0; e < 4; ++e){
    float p1x = cb[2*e],         p1y = cb[2*e+1];
    float p2x = cb[(2*e+2)&7],   p2y = cb[(2*e+3)&7];
    float ex = p2x-p1x, ey = p2y-p1y;
    float d[8];
    #pragma unroll
    for (int q = 0; q < 8; ++q) d[q] = ex*(py[q]-p1y) - ey*(px[q]-p1x);
    float ox[8], oy[8];
    #pragma unroll
    for (int q = 0; q < 8; ++q){ ox[q]=0.f; oy[q]=0.f; }
    int oc = 0;
    #pragma unroll
    for (int q = 0; q < 8; ++q){
      if (q < cnt){
        bool last = (q+1 >= cnt);
        float dn  = last ? d[0]  : d[(q+1)&7];
        bool in0 = (d[q] >= 0.0f), in1 = (dn >= 0.0f);
        if (in0){ emit_pt(ox,oy,oc,px[q],py[q]); oc++; }
        if (in0 != in1){
          float pnx = last ? px[0] : px[(q+1)&7];
          float pny = last ? py[0] : py[(q+1)&7];
          float den = d[q] - dn;
          float t = d[q] / ((den == 0.0f) ? 1.0f : den);
          emit_pt(ox,oy,oc, px[q] + t*(pnx-px[q]), py[q] + t*(pny-py[q]));
          oc++;
        }
      }
    }
    cnt = (oc > 8) ? 8 : oc;
    #pragma unroll
    for (int q = 0; q < 8; ++q){ px[q]=ox[q]; py[q]=oy[q]; }
  }
  if (cnt < 3) return 0.0f;
  float s = 0.0f;
  #pragma unroll
  for (int q = 0; q < 8; ++q){
    if (q < cnt){
      bool last = (q+1 >= cnt);
      float pnx = last ? px[0] : px[(q+1)&7];
      float pny = last ? py[0] : py[(q+1)&7];
      s += px[q]*pny - pnx*py[q];
    }
  }
  return 0.5f*fabsf(s);
}

__global__ __launch_bounds__(256) void k4b_clip(
    const float* __restrict__ geom, const u32* __restrict__ list,
    const u32* __restrict__ gcount, u64* __restrict__ mask)
{
  u32 count = *gcount;
  if (count > PAIR_CAP) count = PAIR_CAP;
  for (u32 idx = blockIdx.x*256 + threadIdx.x; idx < count; idx += gridDim.x*256){
    u32 gt = list[idx];
    int img = (int)(gt >> 22);
    int rem = (int)(gt & ((1u<<22)-1));
    int i = rem >> 11;
    int j = rem & (NCAND-1);
    const float* gi = geom + ((size_t)(img*NCAND + i))*16;
    const float* gj = geom + ((size_t)(img*NCAND + j))*16;
    float inter = quad_inter(gi+5, gj+5);
    float iou = inter / (gi[4] + gj[4] - inter + 1e-7f);
    if (iou > NMS_TH)
      atomicOr(&mask[((size_t)(img*NCAND + i))*32 + (j >> 6)], 1ull << (j & 63));
  }
}

// ---------------------------------------------------------------------------
// K5: sequential greedy suppression, sup in wave-0 registers, early exit at
// the 512th kept row (see R6 notes).
// ---------------------------------------------------------------------------
__global__ __launch_bounds__(1024) void k5_nms_out(
    const u64* __restrict__ mask, const u8* __restrict__ svalid,
    const float* __restrict__ sbox, const float* __restrict__ sscore,
    float* __restrict__ out)
{
  int b = blockIdx.x;
  __shared__ u64 buf[2][128*32];      // 64 KB double buffer
  __shared__ u64 s_kept[32];
  __shared__ u32 pref[32];
  __shared__ u32 s_done, s_R;
  int t = threadIdx.x;
  int wid = t >> 6, lane = t & 63;

  if (t == 0){ s_done = 0; s_R = NCAND - 1; }

  // sup init from svalid: lane l (l<32) builds word l; lanes 32-63 mirror.
  u32 slo = 0, shi = 0;
  if (wid == 0){
    int wl = lane & 31;
    u64 w = 0;
    for (int q = 0; q < 64; ++q)
      if (!svalid[b*NCAND + wl*64 + q]) w |= (1ull << q);
    slo = (u32)w; shi = (u32)(w >> 32);
  }
  // preload chunk 0 (all waves)
  {
    const u64* src = mask + ((size_t)b*NCAND)*32;
    for (int x = t; x < 128*32; x += 1024) buf[0][x] = src[x];
  }
  __syncthreads();

  u32 kcnt = 0;
  bool stopped = false;
  for (int c = 0; c < 16; ++c){
    if (wid != 0){
      if (c + 1 < 16){
        const u64* src = mask + ((size_t)(b*NCAND + (c+1)*128))*32;
        for (int x = t - 64; x < 128*32; x += (1024 - 64))
          buf[(c+1)&1][x] = src[x];
      }
    } else if (!stopped){
      const u64* ch = buf[c&1];
      for (int r8 = 0; r8 < 128 && !stopped; r8 += 8){
        u64 v[8];
        #pragma unroll
        for (int q = 0; q < 8; ++q) v[q] = ch[(r8+q)*32 + (lane & 31)];
        #pragma unroll
        for (int q = 0; q < 8; ++q){
          int gi = c*128 + r8 + q;
          int wi = gi >> 6;                       // wave-uniform
          u32 wlo = (u32)__builtin_amdgcn_readlane((int)slo, wi);
          u32 whi = (u32)__builtin_amdgcn_readlane((int)shi, wi);
          u64 w = ((u64)whi << 32) | wlo;
          u32 keep = (u32)((~w >> (gi & 63)) & 1ull);
          u64 vm = v[q] & (0ull - (u64)keep);     // branchless: keep ? v : 0
          slo |= (u32)vm; shi |= (u32)(vm >> 32);
          kcnt += keep;
          if (kcnt >= (u32)POSTN){                // 512th keep -> stop
            if (lane == 0){ s_done = 1; s_R = (u32)gi; }
            stopped = true;
            break;
          }
        }
      }
    }
    __syncthreads();
    if (s_done) break;
    __syncthreads();
  }
  // publish kept words, range-masked to rows <= R
  if (wid == 0 && lane < 32){
    u32 Rv = s_R;
    int lo_row = (int)lane * 64;
    u64 sup = ((u64)shi << 32) | slo;
    u64 rmask;
    if (lo_row + 63 <= (int)Rv) rmask = ~0ull;
    else if (lo_row > (int)Rv)  rmask = 0ull;
    else                        rmask = (1ull << ((int)Rv - lo_row + 1)) - 1ull;
    s_kept[lane] = (~sup) & rmask;
  }
  __syncthreads();

  // zero-fill this image's output (d_out is poisoned before every launch)
  for (int x = t; x < POSTN*5; x += 1024) out[(size_t)b*POSTN*5 + x] = 0.0f;
  for (int x = t; x < POSTN;   x += 1024) out[(size_t)NB*POSTN*5 + b*POSTN + x] = 0.0f;
  if (t < 32) pref[t] = (u32)__popcll(s_kept[t]);
  __syncthreads();
  if (t == 0){
    u32 run = 0;
    for (int w = 0; w < 32; ++w){ u32 tv = pref[w]; pref[w] = run; run += tv; }
  }
  __syncthreads();
  for (int i = t; i < NCAND; i += 1024){
    u64 kw = s_kept[i >> 6];
    if ((kw >> (i & 63)) & 1ull){
      u32 rank = pref[i >> 6] + (u32)__popcll(kw & ((1ull << (i & 63)) - 1ull));
      if (rank < POSTN){
        const float* bp = sbox + ((size_t)(b*NCAND + i))*5;
        float* op = out + ((size_t)(b*POSTN + rank))*5;
        op[0]=bp[0]; op[1]=bp[1]; op[2]=bp[2]; op[3]=bp[3]; op[4]=bp[4];
        out[(size_t)NB*POSTN*5 + b*POSTN + rank] = sscore[b*NCAND + i];
      }
    }
  }
}

// ---------------------------------------------------------------------------
extern "C" void kernel_launch(void* const* d_in, const int* in_sizes, int n_in,
                              void* d_out, int out_size, void* d_ws, size_t ws_size,
                              hipStream_t stream)
{
  (void)out_size; (void)ws_size;
  const float *obj[4] = {nullptr,nullptr,nullptr,nullptr};
  const float *dlt[4] = {nullptr,nullptr,nullptr,nullptr};
  const float *anchors = nullptr;
  for (int i = 0; i < n_in; ++i){
    int s = in_sizes[i];
    const float* p = (const float*)d_in[i];
    switch (s){
      case 786432:  obj[0] = p; break;
      case 4718592: dlt[0] = p; break;
      case 196608:  obj[1] = p; break;
      case 1179648: dlt[1] = p; break;
      case 49152:   obj[2] = p; break;
      case 294912:  dlt[2] = p; break;
      case 12288:   obj[3] = p; break;
      case 73728:   dlt[3] = p; break;
      case 5222400: anchors = p; break;
      default: break;
    }
  }

  char* wsb = (char*)d_ws;
  size_t off = 0;
  auto alloc = [&](size_t bytes)->void*{
    size_t cur = (off + 255) & ~(size_t)255;
    off = cur + bytes;
    return (void*)(wsb + cur);
  };
  int*   cand_j = (int*)  alloc(16*KSEL*sizeof(int));
  float* cscore = (float*)alloc((size_t)NB*NCAND*sizeof(float));
  u32*   csmono = (u32*)  alloc((size_t)NB*NCAND*sizeof(u32));
  u64*   ctb    = (u64*)  alloc((size_t)NB*NCAND*sizeof(u64));
  float* cbox   = (float*)alloc((size_t)NB*NCAND*5*sizeof(float));
  u8*    cvalid = (u8*)   alloc((size_t)NB*NCAND);
  float* sscore = (float*)alloc((size_t)NB*NCAND*sizeof(float));
  float* sbox   = (float*)alloc((size_t)NB*NCAND*5*sizeof(float));
  u8*    svalid = (u8*)   alloc((size_t)NB*NCAND);
  float* geom   = (float*)alloc((size_t)NB*NCAND*16*sizeof(float));
  float4* aabb4 = (float4*)alloc((size_t)NB*NCAND*sizeof(float4));
  u64*   maskp  = (u64*)  alloc((size_t)NB*NCAND*32*sizeof(u64));
  u32*   plist  = (u32*)  alloc((size_t)PAIR_CAP*sizeof(u32));
  u32*   pcount = (u32*)  alloc(sizeof(u32));
  u32*   ghist  = (u32*)  alloc((size_t)K1_BLOCKS*BINS*sizeof(u32));
  u64*   gtie   = (u64*)  alloc((size_t)16*EQCAP*sizeof(u64));
  u32*   gb0    = (u32*)  alloc(16*sizeof(u32));
  u32*   gcA    = (u32*)  alloc(16*sizeof(u32));
  u32*   emitc  = (u32*)  alloc(16*sizeof(u32));
  u32*   tiec   = (u32*)  alloc(16*sizeof(u32));

  hipMemsetAsync(pcount, 0, sizeof(u32), stream);
  hipMemsetAsync(maskp, 0, (size_t)NB*NCAND*32*sizeof(u64), stream);

  hipLaunchKernelGGL(k1a_hist, dim3(K1_BLOCKS), dim3(1024), 0, stream,
                     obj[0], obj[1], obj[2], obj[3], ghist);
  hipLaunchKernelGGL(k1b_thresh, dim3(16), dim3(1024), 0, stream,
                     ghist, gb0, gcA, emitc, tiec);
  hipLaunchKernelGGL(k1c_classify, dim3(K1_BLOCKS), dim3(1024), 0, stream,
                     obj[0], obj[1], obj[2], obj[3], gb0, emitc, tiec,
                     cand_j, gtie);
  hipLaunchKernelGGL(k1d_tie, dim3(16), dim3(1024), 0, stream,
                     gtie, tiec, gcA, emitc, cand_j);
  hipLaunchKernelGGL(k2_decode, dim3(32), dim3(256), 0, stream,
                     obj[0], obj[1], obj[2], obj[3],
                     dlt[0], dlt[1], dlt[2], dlt[3],
                     anchors, cand_j, cscore, csmono, ctb, cbox, cvalid);
  hipLaunchKernelGGL(k3_rank, dim3(256), dim3(256), 0, stream,
                     csmono, ctb, cscore, cbox, cvalid, sscore, sbox, geom,
                     aabb4, svalid);
  hipLaunchKernelGGL(k4a_aabb, dim3(K4A_BLOCKS), dim3(256), 0, stream,
                     aabb4, plist, pcount);
  hipLaunchKernelGGL(k4b_clip, dim3(256), dim3(256), 0, stream,
                     geom, plist, pcount, maskp);
  hipLaunchKernelGGL(k5_nms_out, dim3(4), dim3(1024), 0, stream,
                     maskp, svalid, sbox, sscore, (float*)d_out);
}

// Round 13
// 201.231 us; speedup vs baseline: 1.9811x; 1.2256x over previous
//
#include <hip/hip_runtime.h>

typedef unsigned int u32;
typedef unsigned long long u64;
typedef unsigned char u8;

#define NB 4
#define T_ANCH 261120
#define NCAND 2048          // candidates per image (4 levels x 512)
#define KSEL 512
#define POSTN 512
#define LOG_MAXF 4.135166556742356f
#define NMS_TH 0.7f
#define LVL_OFF_F 8192.0f
#define BINS 4096           // top-12 bits of mono32
#define EQCAP 8192          // tie-bin capacity (expected ~300-700 occupants)
#define PAIR_CAP (1u<<20)   // 1M compacted pairs
#define K4A_BLOCKS 2048     // 4 i-rows (8192 pairs) per block -> 32 KB LDS
#define K4A_ROWS 4
#define K1_BLOCKS 256       // 64 chunk-blocks per image (48/12/3/1 per level)

__device__ __forceinline__ u32 mono32(float f){
  u32 u = __float_as_uint(f);
  return (u & 0x80000000u) ? ~u : (u | 0x80000000u);
}
__device__ __forceinline__ int lvl_hw(int lvl){ return 65536 >> (2*lvl); }
__device__ __forceinline__ int lvl_off(int lvl){
  return (lvl>0?196608:0) + (lvl>1?49152:0) + (lvl>2?12288:0);
}
// chunk-block mapping: bx in [0,256): b = bx>>6, c = bx&63
__device__ __forceinline__ void k1_map(int bx, int& b, int& lvl, int& ch){
  b = bx >> 6;
  int c = bx & 63;
  if (c < 48){ lvl = 0; ch = c; }
  else if (c < 60){ lvl = 1; ch = c - 48; }
  else if (c < 63){ lvl = 2; ch = c - 60; }
  else { lvl = 3; ch = 0; }
}

// ---------------------------------------------------------------------------
// K1a: per-chunk private histogram of mono32>>20. 256 blocks, 1 float4/thread.
// ---------------------------------------------------------------------------
__global__ __launch_bounds__(1024) void k1a_hist(
    const float* __restrict__ o0, const float* __restrict__ o1,
    const float* __restrict__ o2, const float* __restrict__ o3,
    u32* __restrict__ ghist)
{
  int b, lvl, ch;
  k1_map(blockIdx.x, b, lvl, ch);
  const float* ob = (lvl==0)?o0 : (lvl==1)?o1 : (lvl==2)?o2 : o3;
  int hw = lvl_hw(lvl);
  int size = 3*hw;
  int n4 = size >> 2;
  int i4 = ch*1024 + threadIdx.x;
  __shared__ u32 hist[BINS];
  for (int i = threadIdx.x; i < BINS; i += 1024) hist[i] = 0;
  __syncthreads();
  if (i4 < n4){
    float4 v = ((const float4*)(ob + (size_t)b*size))[i4];
    atomicAdd(&hist[mono32(v.x) >> 20], 1u);
    atomicAdd(&hist[mono32(v.y) >> 20], 1u);
    atomicAdd(&hist[mono32(v.z) >> 20], 1u);
    atomicAdd(&hist[mono32(v.w) >> 20], 1u);
  }
  __syncthreads();
  u32* out = ghist + (size_t)blockIdx.x*BINS;
  for (int i = threadIdx.x; i < BINS; i += 1024) out[i] = hist[i];
}

// ---------------------------------------------------------------------------
// K1b: reduce chunk histograms per (b,lvl); serial threshold walk -> b0,
// cntAbove; zero emit/tie counters.
// ---------------------------------------------------------------------------
__global__ __launch_bounds__(1024) void k1b_thresh(
    const u32* __restrict__ ghist, u32* __restrict__ gb0,
    u32* __restrict__ gcA, u32* __restrict__ emitcnt, u32* __restrict__ tiecnt)
{
  int bid = blockIdx.x;               // 16 = (b,lvl)
  int b = bid >> 2, lvl = bid & 3;
  int base_bx = b*64 + (lvl==0?0 : lvl==1?48 : lvl==2?60 : 63);
  int nch = (lvl==0?48 : lvl==1?12 : lvl==2?3 : 1);
  __shared__ u32 hist[BINS];
  __shared__ u32 coarse[64];
  int t = threadIdx.x;
  u32 c0=0,c1=0,c2=0,c3=0;
  for (int ch = 0; ch < nch; ++ch){
    const u32* h = ghist + (size_t)(base_bx+ch)*BINS;
    c0 += h[4*t+0]; c1 += h[4*t+1]; c2 += h[4*t+2]; c3 += h[4*t+3];
  }
  hist[4*t+0]=c0; hist[4*t+1]=c1; hist[4*t+2]=c2; hist[4*t+3]=c3;
  __syncthreads();
  if (t < 64){
    u32 s = 0;
    for (int z = 0; z < 64; ++z) s += hist[t*64 + z];
    coarse[t] = s;
  }
  __syncthreads();
  if (t == 0){
    u32 acc = 0;
    int cb = 63;
    while (acc + coarse[cb] < (u32)KSEL){ acc += coarse[cb]; --cb; }
    int z = cb*64 + 63;
    while (acc + hist[z] < (u32)KSEL){ acc += hist[z]; --z; }
    gb0[bid] = (u32)z;
    gcA[bid] = acc;
    emitcnt[bid] = 0;
    tiecnt[bid] = 0;
  }
}

// ---------------------------------------------------------------------------
// K1c: classify chunk elements vs b0. LDS lists + ONE global reservation per
// list per block. Emits PERMUTED index j = pix*3 + a (see R4 notes).
// ---------------------------------------------------------------------------
__global__ __launch_bounds__(1024) void k1c_classify(
    const float* __restrict__ o0, const float* __restrict__ o1,
    const float* __restrict__ o2, const float* __restrict__ o3,
    const u32* __restrict__ gb0,
    u32* __restrict__ emitcnt, u32* __restrict__ tiecnt,
    int* __restrict__ cand_j, u64* __restrict__ gtie)
{
  int b, lvl, ch;
  k1_map(blockIdx.x, b, lvl, ch);
  int bid16 = b*4 + lvl;
  const float* ob = (lvl==0)?o0 : (lvl==1)?o1 : (lvl==2)?o2 : o3;
  int hw = lvl_hw(lvl);
  int size = 3*hw;
  int n4 = size >> 2;
  int i4 = ch*1024 + threadIdx.x;

  __shared__ u32 dbuf[KSEL];
  __shared__ u64 tbuf[4096];
  __shared__ u32 dn, tn, dbase, tbase;
  if (threadIdx.x == 0){ dn = 0; tn = 0; }
  __syncthreads();

  u32 b0v = gb0[bid16];
  if (i4 < n4){
    float4 v = ((const float4*)(ob + (size_t)b*size))[i4];
    int L = i4 << 2;
    int a = L / hw;                 // hw % 4 == 0 -> same a for all 4
    int pix = L - a*hw;
    int j0 = pix*3 + a;
    float vv[4] = {v.x, v.y, v.z, v.w};
    #pragma unroll
    for (int q = 0; q < 4; ++q){
      u32 m = mono32(vv[q]);
      u32 bin = m >> 20;
      int j = j0 + 3*q;
      if (bin > b0v){
        u32 s = atomicAdd(&dn, 1u);
        if (s < (u32)KSEL) dbuf[s] = (u32)j;
      } else if (bin == b0v){
        u32 s = atomicAdd(&tn, 1u);
        if (s < 4096u) tbuf[s] = ((u64)m << 32) | (u32)(~(u32)j);
      }
    }
  }
  __syncthreads();
  if (threadIdx.x == 0){
    dbase = dn ? atomicAdd(&emitcnt[bid16], dn) : 0u;
    tbase = tn ? atomicAdd(&tiecnt[bid16], tn) : 0u;
  }
  __syncthreads();
  for (u32 x = threadIdx.x; x < dn; x += 1024){
    u32 s = dbase + x;
    if (s < (u32)KSEL) cand_j[bid16*KSEL + s] = (int)dbuf[x];
  }
  for (u32 x = threadIdx.x; x < tn; x += 1024){
    u32 s = tbase + x;
    if (s < (u32)EQCAP) gtie[(size_t)bid16*EQCAP + s] = tbuf[x];
  }
}

// ---------------------------------------------------------------------------
// K1d: O(n^2) exact rank-select on the tie set; append k = 512-cntAbove
// winners (LDS-aggregated, one global reservation).
// ---------------------------------------------------------------------------
__global__ __launch_bounds__(1024) void k1d_tie(
    const u64* __restrict__ gtie, const u32* __restrict__ tiecnt,
    const u32* __restrict__ gcA, u32* __restrict__ emitcnt,
    int* __restrict__ cand_j)
{
  int bid = blockIdx.x;               // 16
  __shared__ u64 eq[EQCAP];           // 64 KB
  __shared__ u32 wbuf[KSEL];
  __shared__ u32 wn, wbase;
  u32 n = tiecnt[bid]; if (n > (u32)EQCAP) n = (u32)EQCAP;
  u32 k = (u32)KSEL - gcA[bid];
  if (threadIdx.x == 0) wn = 0;
  for (u32 i = threadIdx.x; i < n; i += 1024) eq[i] = gtie[(size_t)bid*EQCAP + i];
  __syncthreads();
  for (u32 i = threadIdx.x; i < n; i += 1024){
    u64 ki = eq[i];
    u32 r = 0;
    for (u32 m = 0; m < n; ++m) r += (eq[m] > ki) ? 1u : 0u;
    if (r < k){
      u32 s = atomicAdd(&wn, 1u);
      if (s < (u32)KSEL) wbuf[s] = (u32)(~(u32)ki);
    }
  }
  __syncthreads();
  if (threadIdx.x == 0) wbase = wn ? atomicAdd(&emitcnt[bid], wn) : 0u;
  __syncthreads();
  for (u32 x = threadIdx.x; x < wn; x += 1024){
    u32 s = wbase + x;
    if (s < (u32)KSEL) cand_j[bid*KSEL + s] = (int)wbuf[x];
  }
}

// ---------------------------------------------------------------------------
// K2: decode the 8192 selected candidates; build sort keys.
// ---------------------------------------------------------------------------
__global__ __launch_bounds__(256) void k2_decode(
    const float* __restrict__ o0, const float* __restrict__ o1,
    const float* __restrict__ o2, const float* __restrict__ o3,
    const float* __restrict__ d0, const float* __restrict__ d1,
    const float* __restrict__ d2, const float* __restrict__ d3,
    const float* __restrict__ anchors,
    const int* __restrict__ cand_j,
    float* __restrict__ cscore, u32* __restrict__ csmono,
    u64* __restrict__ ctb, float* __restrict__ cbox, u8* __restrict__ cvalid)
{
  int c = blockIdx.x*256 + threadIdx.x;
  if (c >= NB*NCAND) return;
  int pair = c >> 9;          // (b,lvl) pair index
  int b = pair >> 2, lvl = pair & 3;
  int j = cand_j[c];
  int hw = lvl_hw(lvl);
  u32 pix = (u32)j / 3u;
  u32 a = (u32)j - pix*3u;
  const float* ob = (lvl==0)?o0 : (lvl==1)?o1 : (lvl==2)?o2 : o3;
  const float* dl = (lvl==0)?d0 : (lvl==1)?d1 : (lvl==2)?d2 : d3;

  float ov = ob[(size_t)(b*3 + (int)a)*hw + pix];
  size_t dbase = ((size_t)(b*3 + (int)a)*6)*(size_t)hw + pix;
  float dx  = dl[dbase + 0*(size_t)hw];
  float dy  = dl[dbase + 1*(size_t)hw];
  float dw  = dl[dbase + 2*(size_t)hw];
  float dh  = dl[dbase + 3*(size_t)hw];
  float dsn = dl[dbase + 4*(size_t)hw];
  float dcs = dl[dbase + 5*(size_t)hw];
  int tt = lvl_off(lvl) + j;
  const float* an = anchors + ((size_t)b*T_ANCH + tt)*5;
  float ax=an[0], ay=an[1], aw=an[2], ah=an[3], aa=an[4];
  dw = fminf(dw, LOG_MAXF); dh = fminf(dh, LOG_MAXF);
  float cx = ax + dx*aw;
  float cy = ay + dy*ah;
  float w  = aw * expf(dw);
  float h  = ah * expf(dh);
  float ang = aa + atan2f(dsn, dcs);
  double sd = 1.0 / (1.0 + exp(-(double)ov));
  float sc = (float)sd;
  bool valid = (w >= 1e-3f) && (h >= 1e-3f) && (sc >= 0.0f);
  cscore[c] = sc;
  csmono[c] = valid ? mono32(sc) : 0u;        // invalid => -inf (stable-sorted by tb)
  // tiebreak: level asc, obj desc, idx asc  (== reference positional order)
  ctb[c] = ((u64)lvl << 50) | ((u64)(u32)(~mono32(ov)) << 18) | (u64)(u32)j;
  cvalid[c] = valid ? 1 : 0;
  float* bb = cbox + (size_t)c*5;
  bb[0]=cx; bb[1]=cy; bb[2]=w; bb[3]=h; bb[4]=ang;
}

// ---------------------------------------------------------------------------
// K3: per-image exact RANK-SORT scatter over 256 blocks (see R12 notes).
// ---------------------------------------------------------------------------
__global__ __launch_bounds__(256) void k3_rank(
    const u32* __restrict__ csmono, const u64* __restrict__ ctb,
    const float* __restrict__ cscore, const float* __restrict__ cbox,
    const u8* __restrict__ cvalid,
    float* __restrict__ sscore, float* __restrict__ sbox,
    float* __restrict__ geom, float4* __restrict__ aabb4,
    u8* __restrict__ svalid)
{
  int b   = blockIdx.x >> 6;          // image
  int blk = blockIdx.x & 63;          // 64 blocks per image, 32 elems each
  __shared__ u32 sm[NCAND];
  __shared__ u64 stb[NCAND];
  __shared__ u32 cnt[32][8];
  for (int k = threadIdx.x; k < NCAND; k += 256){
    sm[k]  = csmono[b*NCAND + k];
    stb[k] = ctb[b*NCAND + k];
  }
  __syncthreads();
  int esub = threadIdx.x >> 3;        // 0..31 element within block
  int ssub = threadIdx.x & 7;         // 0..7 scan slice
  int id = blk*32 + esub;
  u32 ms = sm[id];
  u64 mt = stb[id];
  u32 r = 0;
  #pragma unroll 8
  for (int it = 0; it < 256; ++it){
    int m = it*8 + ssub;
    u32 s2 = sm[m]; u64 t2 = stb[m];
    r += ((s2 > ms) || (s2 == ms && t2 < mt)) ? 1u : 0u;
  }
  cnt[esub][ssub] = r;
  __syncthreads();
  if (ssub == 0){
    u32 rank = 0;
    #pragma unroll
    for (int q = 0; q < 8; ++q) rank += cnt[esub][q];
    int gsrc = b*NCAND + id;
    int gdst = b*NCAND + (int)rank;
    sscore[gdst] = cscore[gsrc];
    svalid[gdst] = cvalid[gsrc];
    float b0 = cbox[(size_t)gsrc*5+0], b1 = cbox[(size_t)gsrc*5+1];
    float b2 = cbox[(size_t)gsrc*5+2], b3 = cbox[(size_t)gsrc*5+3];
    float b4 = cbox[(size_t)gsrc*5+4];
    float* sb = sbox + (size_t)gdst*5;
    sb[0]=b0; sb[1]=b1; sb[2]=b2; sb[3]=b3; sb[4]=b4;
    int lvl = (int)((mt >> 50) & 3ull);
    float offv = (float)lvl * LVL_OFF_F;
    float cx = b0 + offv, cy = b1 + offv, w=b2, h=b3, ang=b4;
    float cc = cosf(ang), sn = sinf(ang);
    float hx = 0.5f*w, hy = 0.5f*h;
    float x0 = cx + hx*cc - hy*sn, y0 = cy + hx*sn + hy*cc;
    float x1 = cx - hx*cc - hy*sn, y1 = cy - hx*sn + hy*cc;
    float x2 = cx - hx*cc + hy*sn, y2 = cy - hx*sn - hy*cc;
    float x3 = cx + hx*cc + hy*sn, y3 = cy + hx*sn - hy*cc;
    float minx = fminf(fminf(x0,x1),fminf(x2,x3));
    float maxx = fmaxf(fmaxf(x0,x1),fmaxf(x2,x3));
    float miny = fminf(fminf(y0,y1),fminf(y2,y3));
    float maxy = fmaxf(fmaxf(y0,y1),fmaxf(y2,y3));
    float* g = geom + (size_t)gdst*16;
    g[0]=minx; g[1]=maxx; g[2]=miny; g[3]=maxy; g[4]=w*h;
    g[5]=x0; g[6]=y0; g[7]=x1; g[8]=y1; g[9]=x2; g[10]=y2; g[11]=x3; g[12]=y3;
    aabb4[gdst] = make_float4(minx, maxx, miny, maxy);
  }
}

// ---------------------------------------------------------------------------
// K4a: AABB filter -> compacted pair list (packed aabb4, 32 KB LDS list,
// one global atomicAdd per block). See R10 notes.
// ---------------------------------------------------------------------------
__global__ __launch_bounds__(256) void k4a_aabb(
    const float4* __restrict__ aabb4,
    u32* __restrict__ list, u32* __restrict__ gcount)
{
  __shared__ u32 lbuf[K4A_ROWS*NCAND];   // 32 KB
  __shared__ u32 lcnt, lbase;
  if (threadIdx.x == 0) lcnt = 0;
  __syncthreads();
  int img = blockIdx.x >> 9;               // 512 blocks per image
  int i0  = (blockIdx.x & 511) * K4A_ROWS;
  #pragma unroll
  for (int r = 0; r < K4A_ROWS; ++r){
    int i = i0 + r;
    float4 gi = aabb4[img*NCAND + i];      // uniform -> cache broadcast
    for (int j = threadIdx.x; j < NCAND; j += 256){
      bool pass = false;
      if (j > i){
        float4 gj = aabb4[img*NCAND + j];
        pass = !(gi.x > gj.y || gj.x > gi.y || gi.z > gj.w || gj.z > gi.w);
      }
      if (pass){
        u32 s = atomicAdd(&lcnt, 1u);
        lbuf[s] = (u32)((img << 22) | (i << 11) | j);
      }
    }
  }
  __syncthreads();
  if (threadIdx.x == 0) lbase = lcnt ? atomicAdd(gcount, lcnt) : 0u;
  __syncthreads();
  u32 n = lcnt, bs = lbase;
  for (u32 x = threadIdx.x; x < n; x += 256){
    u32 idx = bs + x;
    if (idx < PAIR_CAP) list[idx] = lbuf[x];
  }
}

// ---------------------------------------------------------------------------
// K4b: dense clip over the compacted list; scatter bits via atomicOr.
// Also flags each suppressor row i in rowflag (so k5 walks only those).
// ---------------------------------------------------------------------------
__device__ __forceinline__ void emit_pt(float* ox, float* oy, int oc, float x, float y){
  #pragma unroll
  for (int s = 0; s < 8; ++s) if (s == oc){ ox[s] = x; oy[s] = y; }
}

__device__ float quad_inter(const float* ca, const float* cb){
  float px[8], py[8];
  #pragma unroll
  for (int q = 0; q < 8; ++q){ px[q]=0.f; py[q]=0.f; }
  #pragma unroll
  for (int q = 0; q < 4; ++q){ px[q]=ca[2*q]; py[q]=ca[2*q+1]; }
  int cnt = 4;
  #pragma unroll
  for (int e = 0; e < 4; ++e){
    float p1x = cb[2*e],         p1y = cb[2*e+1];
    float p2x = cb[(2*e+2)&7],   p2y = cb[(2*e+3)&7];
    float ex = p2x-p1x, ey = p2y-p1y;
    float d[8];
    #pragma unroll
    for (int q = 0; q < 8; ++q) d[q] = ex*(py[q]-p1y) - ey*(px[q]-p1x);
    float ox[8], oy[8];
    #pragma unroll
    for (int q = 0; q < 8; ++q){ ox[q]=0.f; oy[q]=0.f; }
    int oc = 0;
    #pragma unroll
    for (int q = 0; q < 8; ++q){
      if (q < cnt){
        bool last = (q+1 >= cnt);
        float dn  = last ? d[0]  : d[(q+1)&7];
        bool in0 = (d[q] >= 0.0f), in1 = (dn >= 0.0f);
        if (in0){ emit_pt(ox,oy,oc,px[q],py[q]); oc++; }
        if (in0 != in1){
          float pnx = last ? px[0] : px[(q+1)&7];
          float pny = last ? py[0] : py[(q+1)&7];
          float den = d[q] - dn;
          float t = d[q] / ((den == 0.0f) ? 1.0f : den);
          emit_pt(ox,oy,oc, px[q] + t*(pnx-px[q]), py[q] + t*(pny-py[q]));
          oc++;
        }
      }
    }
    cnt = (oc > 8) ? 8 : oc;
    #pragma unroll
    for (int q = 0; q < 8; ++q){ px[q]=ox[q]; py[q]=oy[q]; }
  }
  if (cnt < 3) return 0.0f;
  float s = 0.0f;
  #pragma unroll
  for (int q = 0; q < 8; ++q){
    if (q < cnt){
      bool last = (q+1 >= cnt);
      float pnx = last ? px[0] : px[(q+1)&7];
      float pny = last ? py[0] : py[(q+1)&7];
      s += px[q]*pny - pnx*py[q];
    }
  }
  return 0.5f*fabsf(s);
}

__global__ __launch_bounds__(256) void k4b_clip(
    const float* __restrict__ geom, const u32* __restrict__ list,
    const u32* __restrict__ gcount, u64* __restrict__ mask,
    u64* __restrict__ rowflag)
{
  u32 count = *gcount;
  if (count > PAIR_CAP) count = PAIR_CAP;
  for (u32 idx = blockIdx.x*256 + threadIdx.x; idx < count; idx += gridDim.x*256){
    u32 gt = list[idx];
    int img = (int)(gt >> 22);
    int rem = (int)(gt & ((1u<<22)-1));
    int i = rem >> 11;
    int j = rem & (NCAND-1);
    const float* gi = geom + ((size_t)(img*NCAND + i))*16;
    const float* gj = geom + ((size_t)(img*NCAND + j))*16;
    float inter = quad_inter(gi+5, gj+5);
    float iou = inter / (gi[4] + gj[4] - inter + 1e-7f);
    if (iou > NMS_TH){
      atomicOr(&mask[((size_t)(img*NCAND + i))*32 + (j >> 6)], 1ull << (j & 63));
      atomicOr(&rowflag[(size_t)img*32 + (i >> 6)], 1ull << (i & 63));
    }
  }
}

// ---------------------------------------------------------------------------
// K5: sparse greedy suppression. Only flagged rows (those with >=1
// suppression bit) can change sup; unflagged rows' mask rows are all-zero,
// so skipping them is exactly the reference semantics. Compact flagged row
// ids (ascending), then wave 0 walks them with sup in registers (lane l
// holds word l), batch-prefetching the 256 B mask rows from global. All
// flagged rows are processed => exact full-reference sup (no early exit).
// ---------------------------------------------------------------------------
__global__ __launch_bounds__(1024) void k5_nms_out(
    const u64* __restrict__ mask, const u64* __restrict__ rowflag,
    const u8* __restrict__ svalid,
    const float* __restrict__ sbox, const float* __restrict__ sscore,
    float* __restrict__ out)
{
  int b = blockIdx.x;
  __shared__ u32 fid[NCAND];
  __shared__ u32 wcnt[32], wpref[32];
  __shared__ u64 s_kept[32];
  __shared__ u32 pref[32];
  __shared__ u32 s_F;
  int t = threadIdx.x;
  int wid = t >> 6, lane = t & 63;

  // ---- compact flagged row ids (ascending: word-major, bit-major) ----
  if (t < 32) wcnt[t] = (u32)__popcll(rowflag[b*32 + t]);
  __syncthreads();
  if (t == 0){
    u32 run = 0;
    for (int w = 0; w < 32; ++w){ wpref[w] = run; run += wcnt[w]; }
    s_F = run;
  }
  __syncthreads();
  if (t < 32){
    u64 fw = rowflag[b*32 + t];
    u32 o = wpref[t];
    while (fw){
      int bpos = __builtin_ctzll(fw);
      fid[o++] = (u32)(t*64 + bpos);
      fw &= fw - 1;
    }
  }
  // zero-fill output concurrently (independent of the walk)
  for (int x = t; x < POSTN*5; x += 1024) out[(size_t)b*POSTN*5 + x] = 0.0f;
  for (int x = t; x < POSTN;   x += 1024) out[(size_t)NB*POSTN*5 + b*POSTN + x] = 0.0f;
  __syncthreads();

  if (wid == 0){
    // sup init from svalid: lane l<32 builds word l (lanes 32-63 mirror)
    u32 slo = 0, shi = 0;
    {
      int wl = lane & 31;
      u64 w = 0;
      for (int q = 0; q < 64; ++q)
        if (!svalid[b*NCAND + wl*64 + q]) w |= (1ull << q);
      slo = (u32)w; shi = (u32)(w >> 32);
    }
    u32 F = s_F;
    const u64* mb = mask + ((size_t)b*NCAND)*32;
    for (u32 f = 0; f < F; f += 8){
      u32 myfid = 0;
      if (f + (lane & 7) < F) myfid = fid[f + (lane & 7)];
      // prefetch the 8 rows (lane&31 owns one u64 word per row)
      u64 v[8];
      #pragma unroll
      for (int q = 0; q < 8; ++q){
        if (f + q < F){
          u32 fq = (u32)__builtin_amdgcn_readlane((int)myfid, q);
          v[q] = mb[(size_t)fq*32 + (lane & 31)];
        } else v[q] = 0ull;
      }
      #pragma unroll
      for (int q = 0; q < 8; ++q){
        if (f + q < F){
          u32 i = (u32)__builtin_amdgcn_readlane((int)myfid, q);
          int wi = (int)(i >> 6);                  // wave-uniform
          u32 wlo = (u32)__builtin_amdgcn_readlane((int)slo, wi);
          u32 whi = (u32)__builtin_amdgcn_readlane((int)shi, wi);
          u64 w = ((u64)whi << 32) | wlo;
          u32 keep = (u32)((~w >> (i & 63)) & 1ull);
          u64 vm = v[q] & (0ull - (u64)keep);      // branchless
          slo |= (u32)vm; shi |= (u32)(vm >> 32);
        }
      }
    }
    if (lane < 32) s_kept[lane] = ~(((u64)shi << 32) | slo);
  }
  __syncthreads();

  if (t < 32) pref[t] = (u32)__popcll(s_kept[t]);
  __syncthreads();
  if (t == 0){
    u32 run = 0;
    for (int w = 0; w < 32; ++w){ u32 tv = pref[w]; pref[w] = run; run += tv; }
  }
  __syncthreads();
  for (int i = t; i < NCAND; i += 1024){
    u64 kw = s_kept[i >> 6];
    if ((kw >> (i & 63)) & 1ull){
      u32 rank = pref[i >> 6] + (u32)__popcll(kw & ((1ull << (i & 63)) - 1ull));
      if (rank < POSTN){
        const float* bp = sbox + ((size_t)(b*NCAND + i))*5;
        float* op = out + ((size_t)(b*POSTN + rank))*5;
        op[0]=bp[0]; op[1]=bp[1]; op[2]=bp[2]; op[3]=bp[3]; op[4]=bp[4];
        out[(size_t)NB*POSTN*5 + b*POSTN + rank] = sscore[b*NCAND + i];
      }
    }
  }
}

// ---------------------------------------------------------------------------
extern "C" void kernel_launch(void* const* d_in, const int* in_sizes, int n_in,
                              void* d_out, int out_size, void* d_ws, size_t ws_size,
                              hipStream_t stream)
{
  (void)out_size; (void)ws_size;
  const float *obj[4] = {nullptr,nullptr,nullptr,nullptr};
  const float *dlt[4] = {nullptr,nullptr,nullptr,nullptr};
  const float *anchors = nullptr;
  for (int i = 0; i < n_in; ++i){
    int s = in_sizes[i];
    const float* p = (const float*)d_in[i];
    switch (s){
      case 786432:  obj[0] = p; break;
      case 4718592: dlt[0] = p; break;
      case 196608:  obj[1] = p; break;
      case 1179648: dlt[1] = p; break;
      case 49152:   obj[2] = p; break;
      case 294912:  dlt[2] = p; break;
      case 12288:   obj[3] = p; break;
      case 73728:   dlt[3] = p; break;
      case 5222400: anchors = p; break;
      default: break;
    }
  }

  char* wsb = (char*)d_ws;
  size_t off = 0;
  auto alloc = [&](size_t bytes)->void*{
    size_t cur = (off + 255) & ~(size_t)255;
    off = cur + bytes;
    return (void*)(wsb + cur);
  };
  int*   cand_j = (int*)  alloc(16*KSEL*sizeof(int));
  float* cscore = (float*)alloc((size_t)NB*NCAND*sizeof(float));
  u32*   csmono = (u32*)  alloc((size_t)NB*NCAND*sizeof(u32));
  u64*   ctb    = (u64*)  alloc((size_t)NB*NCAND*sizeof(u64));
  float* cbox   = (float*)alloc((size_t)NB*NCAND*5*sizeof(float));
  u8*    cvalid = (u8*)   alloc((size_t)NB*NCAND);
  float* sscore = (float*)alloc((size_t)NB*NCAND*sizeof(float));
  float* sbox   = (float*)alloc((size_t)NB*NCAND*5*sizeof(float));
  u8*    svalid = (u8*)   alloc((size_t)NB*NCAND);
  float* geom   = (float*)alloc((size_t)NB*NCAND*16*sizeof(float));
  float4* aabb4 = (float4*)alloc((size_t)NB*NCAND*sizeof(float4));
  // contiguous zero region: maskp (2 MB, 256-mult) | rowflag (1 KB) | pcount
  size_t mask_bytes = (size_t)NB*NCAND*32*sizeof(u64);
  u64*   maskp  = (u64*)  alloc(mask_bytes);
  u64*   rowflag= (u64*)  alloc((size_t)NB*32*sizeof(u64));
  u32*   pcount = (u32*)  alloc(sizeof(u32));
  u32*   plist  = (u32*)  alloc((size_t)PAIR_CAP*sizeof(u32));
  u32*   ghist  = (u32*)  alloc((size_t)K1_BLOCKS*BINS*sizeof(u32));
  u64*   gtie   = (u64*)  alloc((size_t)16*EQCAP*sizeof(u64));
  u32*   gb0    = (u32*)  alloc(16*sizeof(u32));
  u32*   gcA    = (u32*)  alloc(16*sizeof(u32));
  u32*   emitc  = (u32*)  alloc(16*sizeof(u32));
  u32*   tiec   = (u32*)  alloc(16*sizeof(u32));

  // one memset covers maskp + rowflag + pcount (contiguous, 256-aligned)
  hipMemsetAsync(maskp, 0, mask_bytes + (size_t)NB*32*sizeof(u64) + 256, stream);

  hipLaunchKernelGGL(k1a_hist, dim3(K1_BLOCKS), dim3(1024), 0, stream,
                     obj[0], obj[1], obj[2], obj[3], ghist);
  hipLaunchKernelGGL(k1b_thresh, dim3(16), dim3(1024), 0, stream,
                     ghist, gb0, gcA, emitc, tiec);
  hipLaunchKernelGGL(k1c_classify, dim3(K1_BLOCKS), dim3(1024), 0, stream,
                     obj[0], obj[1], obj[2], obj[3], gb0, emitc, tiec,
                     cand_j, gtie);
  hipLaunchKernelGGL(k1d_tie, dim3(16), dim3(1024), 0, stream,
                     gtie, tiec, gcA, emitc, cand_j);
  hipLaunchKernelGGL(k2_decode, dim3(32), dim3(256), 0, stream,
                     obj[0], obj[1], obj[2], obj[3],
                     dlt[0], dlt[1], dlt[2], dlt[3],
                     anchors, cand_j, cscore, csmono, ctb, cbox, cvalid);
  hipLaunchKernelGGL(k3_rank, dim3(256), dim3(256), 0, stream,
                     csmono, ctb, cscore, cbox, cvalid, sscore, sbox, geom,
                     aabb4, svalid);
  hipLaunchKernelGGL(k4a_aabb, dim3(K4A_BLOCKS), dim3(256), 0, stream,
                     aabb4, plist, pcount);
  hipLaunchKernelGGL(k4b_clip, dim3(256), dim3(256), 0, stream,
                     geom, plist, pcount, maskp, rowflag);
  hipLaunchKernelGGL(k5_nms_out, dim3(4), dim3(1024), 0, stream,
                     maskp, rowflag, svalid, sbox, sscore, (float*)d_out);
}